// Round 15
// baseline (416.779 us; speedup 1.0000x reference)
//
#include <hip/hip_runtime.h>

typedef __attribute__((ext_vector_type(8))) short short8;
typedef __attribute__((ext_vector_type(4))) float f32x4;
typedef __attribute__((ext_vector_type(4))) unsigned short us4;
typedef __attribute__((ext_vector_type(8))) unsigned short us8;

#define K_OFF    27
#define M_PAIRS  60000
#define C_DIM    64
#define N_IN     500000
#define N_OUT_C  125000
#define BN_EPS   1e-5f
#define E_TOT    (K_OFF * M_PAIRS)              // 1,620,000

#define TILES_PER_K  ((M_PAIRS + 63) / 64)      // 938 (last tile: 32 valid rows)
#define TOTAL_WT     (K_OFF * TILES_PER_K)      // 25326 wave-tiles

// ---------------------------------------------------------------------------
// ws layout: [contrib 207.36MB][wt][cnt][off][cur][bsum][stats][xb 64MB][pos 6.5MB]
// Tiers: T1 >=279.6MB bf16+ranked | T2 >=273.1 bf16+unranked |
//        T3 >=215.6 f32+ranked    | T4 >=209.1 f32+unranked | else fallback
// ---------------------------------------------------------------------------
#define CONTRIB_BYTES ((size_t)E_TOT * C_DIM * 2)          // 207,360,000
#define WT_OFF    CONTRIB_BYTES
#define WT_BYTES  ((size_t)K_OFF * C_DIM * C_DIM * 2)      // 221,184
#define CNT_OFF   (WT_OFF + WT_BYTES)
#define CNT_BYTES ((size_t)N_OUT_C * 4)
#define OFF_OFF   (CNT_OFF + CNT_BYTES)
#define CUR_OFF   (OFF_OFF + CNT_BYTES)
#define BSUM_OFF  (CUR_OFF + CNT_BYTES)
#define ST_OFF    (BSUM_OFF + 4096)
#define XB_OFF    ((ST_OFF + 512 + 255) & ~(size_t)255)
#define XB_BYTES  ((size_t)N_IN * C_DIM * 2)               // 64,000,000
#define POS_BYTES ((size_t)E_TOT * 4)                      // 6,480,000
#define WS_MID    XB_OFF
#define WS_T3     (XB_OFF + POS_BYTES)
#define WS_FULL   (XB_OFF + XB_BYTES)
#define WS_T1     (XB_OFF + XB_BYTES + POS_BYTES)

#define SCAN_BS 256
#define SCAN_NB ((N_OUT_C + SCAN_BS - 1) / SCAN_BS)        // 489

#define PREP_XBLK 2048
#define PREP_WBLK ((K_OFF * C_DIM * C_DIM + 255) / 256)    // 432
#define PREP_HBLK 1024

__device__ __forceinline__ unsigned short f32_to_bf16(float f) {
    unsigned u = __float_as_uint(f);
    u += 0x7FFFu + ((u >> 16) & 1u);          // RNE
    return (unsigned short)(u >> 16);
}
__device__ __forceinline__ float bf16f(unsigned short u) {
    return __uint_as_float((unsigned)u << 16);
}

// ---------------------------------------------------------------------------
// prep: fused conv_x (nt-load x -> bf16 xb) + conv_w (W -> wt B^T bf16) +
// hist (cnt[o]++; ranked path stores each entry's LOCAL RANK = atomic return).
// ---------------------------------------------------------------------------
__global__ __launch_bounds__(256) void prep(
    const float* __restrict__ x, unsigned short* __restrict__ xb,
    const float* __restrict__ W, unsigned short* __restrict__ wt,
    const int* __restrict__ out_idx, unsigned* __restrict__ cnt,
    unsigned* __restrict__ pos, int nx)
{
    int b = blockIdx.x;
    if (b < nx) {                      // ---- x fp32 -> bf16 (nt read-once) ----
        const int tid = b * 256 + threadIdx.x;
        const int T   = nx * 256;
        const int n4  = N_IN * C_DIM / 4;
        const f32x4* x4 = (const f32x4*)x;
        us4* b4 = (us4*)xb;
        for (int i = tid; i < n4; i += T) {
            f32x4 v = __builtin_nontemporal_load(&x4[i]);
            us4 o;
            o.x = f32_to_bf16(v.x); o.y = f32_to_bf16(v.y);
            o.z = f32_to_bf16(v.z); o.w = f32_to_bf16(v.w);
            b4[i] = o;
        }
        return;
    }
    b -= nx;
    if (b < PREP_WBLK) {               // ---- W[k][c][d] -> wt[k][d][c] ----
        const int tid = b * 256 + threadIdx.x;
        if (tid < K_OFF * C_DIM * C_DIM) {
            const int c = tid & 63;
            const int d = (tid >> 6) & 63;
            const int k = tid >> 12;
            wt[tid] = f32_to_bf16(W[(k << 12) + (c << 6) + d]);
        }
        return;
    }
    b -= PREP_WBLK;                    // ---- histogram + local rank ----
    if (pos) {
        for (int e = b * 256 + threadIdx.x; e < E_TOT; e += PREP_HBLK * 256)
            pos[e] = atomicAdd(&cnt[out_idx[e]], 1u);
    } else {
        for (int e = b * 256 + threadIdx.x; e < E_TOT; e += PREP_HBLK * 256)
            atomicAdd(&cnt[out_idx[e]], 1u);
    }
}

// ---- 3-kernel exclusive scan of cnt -> off (final); cur = off -------------
__global__ __launch_bounds__(SCAN_BS) void scan_a(const unsigned* __restrict__ cnt,
                                                  unsigned* __restrict__ off,
                                                  unsigned* __restrict__ bsum) {
    __shared__ unsigned s[SCAN_BS];
    const int idx = blockIdx.x * SCAN_BS + threadIdx.x;
    const unsigned v = (idx < N_OUT_C) ? cnt[idx] : 0u;
    s[threadIdx.x] = v;
    __syncthreads();
    for (int d = 1; d < SCAN_BS; d <<= 1) {
        unsigned t = (threadIdx.x >= d) ? s[threadIdx.x - d] : 0u;
        __syncthreads();
        s[threadIdx.x] += t;
        __syncthreads();
    }
    if (idx < N_OUT_C) off[idx] = s[threadIdx.x] - v;   // exclusive (local)
    if (threadIdx.x == SCAN_BS - 1) bsum[blockIdx.x] = s[threadIdx.x];
}

__global__ __launch_bounds__(512) void scan_b(unsigned* __restrict__ bsum) {
    __shared__ unsigned s[512];
    const unsigned v = (threadIdx.x < SCAN_NB) ? bsum[threadIdx.x] : 0u;
    s[threadIdx.x] = v;
    __syncthreads();
    for (int d = 1; d < 512; d <<= 1) {
        unsigned t = (threadIdx.x >= d) ? s[threadIdx.x - d] : 0u;
        __syncthreads();
        s[threadIdx.x] += t;
        __syncthreads();
    }
    if (threadIdx.x < SCAN_NB) bsum[threadIdx.x] = s[threadIdx.x] - v;  // exclusive
}

__global__ __launch_bounds__(SCAN_BS) void scan_c(unsigned* __restrict__ off,
                                                  unsigned* __restrict__ cur,
                                                  const unsigned* __restrict__ bsum) {
    const int idx = blockIdx.x * SCAN_BS + threadIdx.x;
    if (idx < N_OUT_C) {
        const unsigned o = off[idx] + bsum[blockIdx.x];
        off[idx] = o;       // final global offset
        cur[idx] = o;       // running cursor (unranked path only)
    }
}

// ---------------------------------------------------------------------------
// Phase 1: 64-row MFMA tiles. RANKED: slot = off[o] + pos_local[e] (two
// loads, NO atomics). Per-lane bf16 short stores.
// A layout (verified r4/r5): lane(lg,lr) row=rt*16+lr, k=ks*32+lg*8..+8.
// C/D: channel = ct*16+lr, row = rt*16 + lg*4 + j.
// ---------------------------------------------------------------------------
template<bool BF16G, bool RANKED>
__global__ __launch_bounds__(256, 4) void mfma_contrib(
    const float* __restrict__ x, const unsigned short* __restrict__ xb,
    const unsigned short* __restrict__ wt,
    const int* __restrict__ in_idx, const int* __restrict__ out_idx,
    const unsigned* __restrict__ offf, unsigned* __restrict__ cursor,
    const unsigned* __restrict__ pos_local, unsigned short* __restrict__ contrib)
{
    const int gwave = blockIdx.x * 4 + (threadIdx.x >> 6);
    if (gwave >= TOTAL_WT) return;
    const int lane = threadIdx.x & 63;
    const int lg = lane >> 4;            // 0..3
    const int lr = lane & 15;            // 0..15

    const int k  = gwave / TILES_PER_K;
    const int t  = gwave % TILES_PER_K;
    const int m0 = t * 64;
    const int kbase = k * M_PAIRS;

    // B fragments: bfr[ks][ct] holds wt[k][ct*16+lr][ks*32+lg*8 .. +8]
    short8 bfr[2][4];
    const unsigned short* wtk = wt + (size_t)k * C_DIM * C_DIM;
#pragma unroll
    for (int ks = 0; ks < 2; ++ks)
#pragma unroll
        for (int ct = 0; ct < 4; ++ct)
            bfr[ks][ct] = *(const short8*)(wtk + (ct * 16 + lr) * C_DIM + ks * 32 + lg * 8);

    // Slot for this lane's row (lane = row within tile).
    int pos = -1;
    {
        const int mrow = m0 + lane;
        if (mrow < M_PAIRS) {
            const int e = kbase + mrow;
            if constexpr (RANKED)
                pos = (int)(offf[out_idx[e]] + pos_local[e]);
            else
                pos = (int)atomicAdd(&cursor[out_idx[e]], 1u);
        }
    }

    // Row gather indices for A (this lane serves row rt*16+lr)
    int aidx[4];
#pragma unroll
    for (int rt = 0; rt < 4; ++rt) {
        const int m = m0 + rt * 16 + lr;
        aidx[rt] = (m < M_PAIRS) ? in_idx[kbase + m] : -1;
    }

    f32x4 acc[4][4] = {};
#pragma unroll
    for (int ks = 0; ks < 2; ++ks) {
#pragma unroll
        for (int rt = 0; rt < 4; ++rt) {
            short8 a = {};
            if (aidx[rt] >= 0) {
                if constexpr (BF16G) {
                    a = *(const short8*)(xb + (size_t)aidx[rt] * C_DIM + ks * 32 + lg * 8);
                } else {
                    const float* xr = x + (size_t)aidx[rt] * C_DIM + ks * 32 + lg * 8;
                    float4 f0 = *(const float4*)xr;
                    float4 f1 = *(const float4*)(xr + 4);
                    a[0] = (short)f32_to_bf16(f0.x); a[1] = (short)f32_to_bf16(f0.y);
                    a[2] = (short)f32_to_bf16(f0.z); a[3] = (short)f32_to_bf16(f0.w);
                    a[4] = (short)f32_to_bf16(f1.x); a[5] = (short)f32_to_bf16(f1.y);
                    a[6] = (short)f32_to_bf16(f1.z); a[7] = (short)f32_to_bf16(f1.w);
                }
            }
#pragma unroll
            for (int ct = 0; ct < 4; ++ct)
                acc[rt][ct] = __builtin_amdgcn_mfma_f32_16x16x32_bf16(
                    a, bfr[ks][ct], acc[rt][ct], 0, 0, 0);
        }
    }

    // Store contrib rows: row r = rt*16 + lg*4 + j; channel d = ct*16 + lr.
#pragma unroll
    for (int rt = 0; rt < 4; ++rt) {
#pragma unroll
        for (int j = 0; j < 4; ++j) {
            const int r = rt * 16 + lg * 4 + j;
            const int p = __shfl(pos, r);
            if (p >= 0) {
                unsigned short* dst = contrib + (size_t)p * C_DIM + lr;
#pragma unroll
                for (int ct = 0; ct < 4; ++ct)
                    dst[ct * 16] = f32_to_bf16(acc[rt][ct][j]);
            }
        }
    }
}

// ---------------------------------------------------------------------------
// Phase 2: streaming segmented reduce + fused BN stats.
// r15: MLP fix WITH occupancy pinned (r13's confound: unroll raised VGPR ->
// occupancy 65->37%, cancelling the MLP gain). Lane = (rg 0..7 row-slot,
// lo 0..7 channel-oct): ushort8 = 16B/lane (G13 sweet spot), one instr = 8
// rows = 1KB. Fixed 4-deep predicated unroll (covers n<=32; Poisson mean 13)
// -> 4 independent loads in flight; launch_bounds(256,8) caps VGPR at 64 so
// 8 waves/SIMD is guaranteed. Keeps r14's synchronized strided-o window.
// ---------------------------------------------------------------------------
__global__ __launch_bounds__(256, 8) void reduce_bn(
    const unsigned short* __restrict__ contrib, const unsigned* __restrict__ off,
    const unsigned* __restrict__ cnt, float* __restrict__ out,
    float* __restrict__ stats)
{
    __shared__ float ls[128];
    if (threadIdx.x < 128) ls[threadIdx.x] = 0.f;
    __syncthreads();
    const int lane = threadIdx.x & 63;
    const int rg = lane >> 3;            // row slot 0..7
    const int lo = lane & 7;             // channel oct 0..7 (8 ch = 16B)
    const int wid  = blockIdx.x * 4 + (threadIdx.x >> 6);
    const int NW   = gridDim.x * 4;      // 8192 waves = full residency

    float ts[8] = {}, tq[8] = {};
    for (int o = wid; o < N_OUT_C; o += NW) {
        const unsigned base = off[o];
        const int n = (int)cnt[o];
        const unsigned short* p = contrib + (size_t)base * C_DIM + lo * 8;

        // 4 predicated 16B loads, statically indexed -> all in flight.
        us8 u[4];
#pragma unroll
        for (int c = 0; c < 4; ++c) {
            const int i = rg + 8 * c;
            us8 v = {0, 0, 0, 0, 0, 0, 0, 0};
            if (i < n) v = *(const us8*)(p + (size_t)i * C_DIM);
            u[c] = v;
        }
        float s[8] = {};
#pragma unroll
        for (int c = 0; c < 4; ++c)
#pragma unroll
            for (int j = 0; j < 8; ++j)
                s[j] += bf16f(u[c][j]);
        // Generic tail (n>32: essentially never at Poisson mean 13).
        for (int i = 32 + rg; i < n; i += 8) {
            const us8 v = *(const us8*)(p + (size_t)i * C_DIM);
#pragma unroll
            for (int j = 0; j < 8; ++j) s[j] += bf16f(v[j]);
        }
        // Reduce across the 8 row-slots (lane bits 3,4,5).
#pragma unroll
        for (int j = 0; j < 8; ++j) {
            s[j] += __shfl_xor(s[j], 8);
            s[j] += __shfl_xor(s[j], 16);
            s[j] += __shfl_xor(s[j], 32);
        }
        if (rg == 0) {
            float* ob = out + (size_t)o * C_DIM + lo * 8;
            *(float4*)(ob)     = make_float4(s[0], s[1], s[2], s[3]);
            *(float4*)(ob + 4) = make_float4(s[4], s[5], s[6], s[7]);
#pragma unroll
            for (int j = 0; j < 8; ++j) {
                ts[j] += s[j];
                tq[j] = fmaf(s[j], s[j], tq[j]);
            }
        }
    }
    if (rg == 0) {
#pragma unroll
        for (int j = 0; j < 8; ++j) {
            atomicAdd(&ls[lo * 8 + j], ts[j]);
            atomicAdd(&ls[64 + lo * 8 + j], tq[j]);
        }
    }
    __syncthreads();
    if (threadIdx.x < 128) unsafeAtomicAdd(&stats[threadIdx.x], ls[threadIdx.x]);
}

// ---- BN apply (in-place on f32 out; final write nontemporal) --------------
__global__ __launch_bounds__(256) void bn_apply_f32(
    float* __restrict__ out, const float* __restrict__ stats,
    const float* __restrict__ gamma, const float* __restrict__ beta)
{
    __shared__ float ssc[C_DIM], ssh[C_DIM];
    if (threadIdx.x < C_DIM) {
        const float inv_n = 1.0f / (float)N_OUT_C;
        float mean = stats[threadIdx.x] * inv_n;
        float var  = stats[C_DIM + threadIdx.x] * inv_n - mean * mean;
        float inv  = rsqrtf(var + BN_EPS);
        float s    = inv * gamma[threadIdx.x];
        ssc[threadIdx.x] = s;
        ssh[threadIdx.x] = beta[threadIdx.x] - mean * s;
    }
    __syncthreads();
    const int tid = blockIdx.x * blockDim.x + threadIdx.x;
    const int T   = gridDim.x * blockDim.x;
    const int cq  = (tid & 15) * 4;
    const int total4 = N_OUT_C * C_DIM / 4;
    const f32x4 sc = {ssc[cq], ssc[cq+1], ssc[cq+2], ssc[cq+3]};
    const f32x4 sh = {ssh[cq], ssh[cq+1], ssh[cq+2], ssh[cq+3]};
    f32x4* o4 = (f32x4*)out;
    for (int i = tid; i < total4; i += T) {
        f32x4 v = o4[i];
        v = v * sc + sh;
        __builtin_nontemporal_store(v, &o4[i]);
    }
}

// ===========================================================================
// Fallback (tiny ws): round-3 scalar path, f32 atomics into d_out.
// ===========================================================================
#define FCHUNKS  37
#define FWPK     (FCHUNKS * 4)
#define FSPAN    ((M_PAIRS + FWPK - 1) / FWPK)

__global__ __launch_bounds__(256, 4) void conv_scatter(
    const float* __restrict__ x, const float* __restrict__ W,
    const int* __restrict__ in_idx, const int* __restrict__ out_idx,
    float* __restrict__ out)
{
    const int k     = blockIdx.x / FCHUNKS;
    const int chunk = blockIdx.x % FCHUNKS;
    const int wid   = chunk * 4 + (threadIdx.x >> 6);
    const int lane  = threadIdx.x & 63;
    float wcol[C_DIM];
    const float* Wk = W + (size_t)k * C_DIM * C_DIM;
#pragma unroll
    for (int c = 0; c < C_DIM; ++c) wcol[c] = Wk[c * C_DIM + lane];
    const int kbase = k * M_PAIRS;
    const int m0 = wid * FSPAN;
    const int m1 = (m0 + FSPAN < M_PAIRS) ? m0 + FSPAN : M_PAIRS;
    for (int m = m0; m < m1; ++m) {
        int ii = __builtin_amdgcn_readfirstlane(in_idx[kbase + m]);
        int oi = __builtin_amdgcn_readfirstlane(out_idx[kbase + m]);
        const float* xr = x + (size_t)ii * C_DIM;
        float a0=0.f,a1=0.f,a2=0.f,a3=0.f;
#pragma unroll
        for (int c = 0; c < C_DIM; c += 4) {
            a0 = fmaf(xr[c+0], wcol[c+0], a0);
            a1 = fmaf(xr[c+1], wcol[c+1], a1);
            a2 = fmaf(xr[c+2], wcol[c+2], a2);
            a3 = fmaf(xr[c+3], wcol[c+3], a3);
        }
        unsafeAtomicAdd(out + (size_t)oi * C_DIM + lane, (a0+a1)+(a2+a3));
    }
}

__global__ __launch_bounds__(256) void bn_stats_f32(
    const float* __restrict__ acc, float* __restrict__ stats)
{
    const int tid = blockIdx.x * blockDim.x + threadIdx.x;
    const int T   = gridDim.x * blockDim.x;
    const int cq  = (tid & 15) * 4;
    const int total4 = N_OUT_C * C_DIM / 4;
    float s0=0,s1=0,s2=0,s3=0,q0=0,q1=0,q2=0,q3=0;
    const float4* a4 = (const float4*)acc;
    for (int i = tid; i < total4; i += T) {
        float4 v = a4[i];
        s0+=v.x; q0=fmaf(v.x,v.x,q0);
        s1+=v.y; q1=fmaf(v.y,v.y,q1);
        s2+=v.z; q2=fmaf(v.z,v.z,q2);
        s3+=v.w; q3=fmaf(v.w,v.w,q3);
    }
    __shared__ float ls[128];
    if (threadIdx.x < 128) ls[threadIdx.x] = 0.f;
    __syncthreads();
    atomicAdd(&ls[cq+0],s0); atomicAdd(&ls[cq+1],s1);
    atomicAdd(&ls[cq+2],s2); atomicAdd(&ls[cq+3],s3);
    atomicAdd(&ls[64+cq+0],q0); atomicAdd(&ls[64+cq+1],q1);
    atomicAdd(&ls[64+cq+2],q2); atomicAdd(&ls[64+cq+3],q3);
    __syncthreads();
    if (threadIdx.x < 128) unsafeAtomicAdd(&stats[threadIdx.x], ls[threadIdx.x]);
}

__global__ __launch_bounds__(256) void bn_apply_fb(
    float* __restrict__ out, const float* __restrict__ stats,
    const float* __restrict__ gamma, const float* __restrict__ beta)
{
    __shared__ float ssc[C_DIM], ssh[C_DIM];
    if (threadIdx.x < C_DIM) {
        const float inv_n = 1.0f / (float)N_OUT_C;
        float mean = stats[threadIdx.x] * inv_n;
        float var  = stats[C_DIM + threadIdx.x] * inv_n - mean * mean;
        float inv  = rsqrtf(var + BN_EPS);
        float s    = inv * gamma[threadIdx.x];
        ssc[threadIdx.x] = s;
        ssh[threadIdx.x] = beta[threadIdx.x] - mean * s;
    }
    __syncthreads();
    const int tid = blockIdx.x * blockDim.x + threadIdx.x;
    const int T   = gridDim.x * blockDim.x;
    const int cq  = (tid & 15) * 4;
    const int total4 = N_OUT_C * C_DIM / 4;
    const float4 sc = make_float4(ssc[cq], ssc[cq+1], ssc[cq+2], ssc[cq+3]);
    const float4 sh = make_float4(ssh[cq], ssh[cq+1], ssh[cq+2], ssh[cq+3]);
    float4* o4 = (float4*)out;
    for (int i = tid; i < total4; i += T) {
        float4 v = o4[i];
        v.x = fmaf(v.x, sc.x, sh.x);
        v.y = fmaf(v.y, sc.y, sh.y);
        v.z = fmaf(v.z, sc.z, sh.z);
        v.w = fmaf(v.w, sc.w, sh.w);
        o4[i] = v;
    }
}

// ---------------------------------------------------------------------------
extern "C" void kernel_launch(void* const* d_in, const int* in_sizes, int n_in,
                              void* d_out, int out_size, void* d_ws, size_t ws_size,
                              hipStream_t stream)
{
    const float* x       = (const float*)d_in[0];
    const float* W       = (const float*)d_in[1];
    const float* gamma   = (const float*)d_in[2];
    const float* beta    = (const float*)d_in[3];
    const int*   in_idx  = (const int*)d_in[4];
    const int*   out_idx = (const int*)d_in[5];
    float* out = (float*)d_out;

    if (ws_size >= WS_MID) {
        unsigned short* contrib = (unsigned short*)d_ws;
        unsigned short* wt      = (unsigned short*)((char*)d_ws + WT_OFF);
        unsigned* cnt           = (unsigned*)((char*)d_ws + CNT_OFF);
        unsigned* off           = (unsigned*)((char*)d_ws + OFF_OFF);
        unsigned* cur           = (unsigned*)((char*)d_ws + CUR_OFF);
        unsigned* bsum          = (unsigned*)((char*)d_ws + BSUM_OFF);
        float* stats            = (float*)((char*)d_ws + ST_OFF);
        unsigned short* xb      = (unsigned short*)((char*)d_ws + XB_OFF);

        const bool full   = (ws_size >= WS_FULL);
        const bool ranked = full ? (ws_size >= WS_T1) : (ws_size >= WS_T3);
        unsigned* pos = ranked
            ? (unsigned*)((char*)d_ws + (full ? (XB_OFF + XB_BYTES) : XB_OFF))
            : nullptr;
        const int nx = full ? PREP_XBLK : 0;

        hipMemsetAsync(cnt, 0, CNT_BYTES, stream);
        hipMemsetAsync(stats, 0, 128 * sizeof(float), stream);
        prep<<<nx + PREP_WBLK + PREP_HBLK, 256, 0, stream>>>(
            x, xb, W, wt, out_idx, cnt, pos, nx);
        scan_a<<<SCAN_NB, SCAN_BS, 0, stream>>>(cnt, off, bsum);
        scan_b<<<1, 512, 0, stream>>>(bsum);
        scan_c<<<SCAN_NB, SCAN_BS, 0, stream>>>(off, cur, bsum);

        const int cgrid = (TOTAL_WT + 3) / 4;
        if (full && ranked)
            mfma_contrib<true, true><<<cgrid, 256, 0, stream>>>(
                x, xb, wt, in_idx, out_idx, off, cur, pos, contrib);
        else if (full)
            mfma_contrib<true, false><<<cgrid, 256, 0, stream>>>(
                x, xb, wt, in_idx, out_idx, off, cur, pos, contrib);
        else if (ranked)
            mfma_contrib<false, true><<<cgrid, 256, 0, stream>>>(
                x, xb, wt, in_idx, out_idx, off, cur, pos, contrib);
        else
            mfma_contrib<false, false><<<cgrid, 256, 0, stream>>>(
                x, xb, wt, in_idx, out_idx, off, cur, pos, contrib);

        reduce_bn<<<2048, 256, 0, stream>>>(contrib, off, cnt, out, stats);
        bn_apply_f32<<<1024, 256, 0, stream>>>(out, stats, gamma, beta);
    } else {
        float* stats = (float*)d_ws;
        hipMemsetAsync(out, 0, (size_t)N_OUT_C * C_DIM * sizeof(float), stream);
        hipMemsetAsync(stats, 0, 128 * sizeof(float), stream);
        conv_scatter<<<K_OFF * FCHUNKS, 256, 0, stream>>>(x, W, in_idx, out_idx, out);
        bn_stats_f32<<<512, 256, 0, stream>>>(out, stats);
        bn_apply_fb<<<1024, 256, 0, stream>>>(out, stats, gamma, beta);
    }
}

// Round 16
// 358.429 us; speedup vs baseline: 1.1628x; 1.1628x over previous
//
#include <hip/hip_runtime.h>

typedef __attribute__((ext_vector_type(8))) short short8;
typedef __attribute__((ext_vector_type(4))) float f32x4;
typedef __attribute__((ext_vector_type(4))) unsigned short us4;

#define K_OFF    27
#define M_PAIRS  60000
#define C_DIM    64
#define N_IN     500000
#define N_OUT_C  125000
#define BN_EPS   1e-5f
#define E_TOT    (K_OFF * M_PAIRS)              // 1,620,000

#define TILES_PER_K  ((M_PAIRS + 63) / 64)      // 938 (last tile: 32 valid rows)
#define TOTAL_WT     (K_OFF * TILES_PER_K)      // 25326 wave-tiles

// ---------------------------------------------------------------------------
// ws layout: [contrib 207.36MB][wt][cnt][off][cur][bsum][stats][xb 64MB][pos 6.5MB]
// ---------------------------------------------------------------------------
#define CONTRIB_BYTES ((size_t)E_TOT * C_DIM * 2)          // 207,360,000
#define WT_OFF    CONTRIB_BYTES
#define WT_BYTES  ((size_t)K_OFF * C_DIM * C_DIM * 2)      // 221,184
#define CNT_OFF   (WT_OFF + WT_BYTES)
#define CNT_BYTES ((size_t)N_OUT_C * 4)
#define OFF_OFF   (CNT_OFF + CNT_BYTES)
#define CUR_OFF   (OFF_OFF + CNT_BYTES)
#define BSUM_OFF  (CUR_OFF + CNT_BYTES)
#define ST_OFF    (BSUM_OFF + 4096)
#define XB_OFF    ((ST_OFF + 512 + 255) & ~(size_t)255)
#define XB_BYTES  ((size_t)N_IN * C_DIM * 2)               // 64,000,000
#define POS_BYTES ((size_t)E_TOT * 4)                      // 6,480,000
#define WS_MID    XB_OFF
#define WS_T3     (XB_OFF + POS_BYTES)
#define WS_FULL   (XB_OFF + XB_BYTES)
#define WS_T1     (XB_OFF + XB_BYTES + POS_BYTES)

#define SCAN_BS 256
#define SCAN_NB ((N_OUT_C + SCAN_BS - 1) / SCAN_BS)        // 489

#define PREP_XBLK 2048
#define PREP_WBLK ((K_OFF * C_DIM * C_DIM + 255) / 256)    // 432
#define PREP_HBLK 1024

__device__ __forceinline__ unsigned short f32_to_bf16(float f) {
    unsigned u = __float_as_uint(f);
    u += 0x7FFFu + ((u >> 16) & 1u);          // RNE
    return (unsigned short)(u >> 16);
}
__device__ __forceinline__ float bf16f(unsigned short u) {
    return __uint_as_float((unsigned)u << 16);
}

// ---------------------------------------------------------------------------
// prep: fused conv_x (nt-load x -> bf16 xb) + conv_w (W -> wt B^T bf16) +
// hist (cnt[o]++; ranked path stores each entry's LOCAL RANK = atomic return).
// ---------------------------------------------------------------------------
__global__ __launch_bounds__(256) void prep(
    const float* __restrict__ x, unsigned short* __restrict__ xb,
    const float* __restrict__ W, unsigned short* __restrict__ wt,
    const int* __restrict__ out_idx, unsigned* __restrict__ cnt,
    unsigned* __restrict__ pos, int nx)
{
    int b = blockIdx.x;
    if (b < nx) {                      // ---- x fp32 -> bf16 (nt read-once) ----
        const int tid = b * 256 + threadIdx.x;
        const int T   = nx * 256;
        const int n4  = N_IN * C_DIM / 4;
        const f32x4* x4 = (const f32x4*)x;
        us4* b4 = (us4*)xb;
        for (int i = tid; i < n4; i += T) {
            f32x4 v = __builtin_nontemporal_load(&x4[i]);
            us4 o;
            o.x = f32_to_bf16(v.x); o.y = f32_to_bf16(v.y);
            o.z = f32_to_bf16(v.z); o.w = f32_to_bf16(v.w);
            b4[i] = o;
        }
        return;
    }
    b -= nx;
    if (b < PREP_WBLK) {               // ---- W[k][c][d] -> wt[k][d][c] ----
        const int tid = b * 256 + threadIdx.x;
        if (tid < K_OFF * C_DIM * C_DIM) {
            const int c = tid & 63;
            const int d = (tid >> 6) & 63;
            const int k = tid >> 12;
            wt[tid] = f32_to_bf16(W[(k << 12) + (c << 6) + d]);
        }
        return;
    }
    b -= PREP_WBLK;                    // ---- histogram + local rank ----
    if (pos) {
        for (int e = b * 256 + threadIdx.x; e < E_TOT; e += PREP_HBLK * 256)
            pos[e] = atomicAdd(&cnt[out_idx[e]], 1u);
    } else {
        for (int e = b * 256 + threadIdx.x; e < E_TOT; e += PREP_HBLK * 256)
            atomicAdd(&cnt[out_idx[e]], 1u);
    }
}

// ---- 3-kernel exclusive scan of cnt -> off (final); cur = off -------------
__global__ __launch_bounds__(SCAN_BS) void scan_a(const unsigned* __restrict__ cnt,
                                                  unsigned* __restrict__ off,
                                                  unsigned* __restrict__ bsum) {
    __shared__ unsigned s[SCAN_BS];
    const int idx = blockIdx.x * SCAN_BS + threadIdx.x;
    const unsigned v = (idx < N_OUT_C) ? cnt[idx] : 0u;
    s[threadIdx.x] = v;
    __syncthreads();
    for (int d = 1; d < SCAN_BS; d <<= 1) {
        unsigned t = (threadIdx.x >= d) ? s[threadIdx.x - d] : 0u;
        __syncthreads();
        s[threadIdx.x] += t;
        __syncthreads();
    }
    if (idx < N_OUT_C) off[idx] = s[threadIdx.x] - v;   // exclusive (local)
    if (threadIdx.x == SCAN_BS - 1) bsum[blockIdx.x] = s[threadIdx.x];
}

__global__ __launch_bounds__(512) void scan_b(unsigned* __restrict__ bsum) {
    __shared__ unsigned s[512];
    const unsigned v = (threadIdx.x < SCAN_NB) ? bsum[threadIdx.x] : 0u;
    s[threadIdx.x] = v;
    __syncthreads();
    for (int d = 1; d < 512; d <<= 1) {
        unsigned t = (threadIdx.x >= d) ? s[threadIdx.x - d] : 0u;
        __syncthreads();
        s[threadIdx.x] += t;
        __syncthreads();
    }
    if (threadIdx.x < SCAN_NB) bsum[threadIdx.x] = s[threadIdx.x] - v;  // exclusive
}

__global__ __launch_bounds__(SCAN_BS) void scan_c(unsigned* __restrict__ off,
                                                  unsigned* __restrict__ cur,
                                                  const unsigned* __restrict__ bsum) {
    const int idx = blockIdx.x * SCAN_BS + threadIdx.x;
    if (idx < N_OUT_C) {
        const unsigned o = off[idx] + bsum[blockIdx.x];
        off[idx] = o;       // final global offset
        cur[idx] = o;       // running cursor (unranked path only)
    }
}

// ---------------------------------------------------------------------------
// Phase 1: 64-row MFMA tiles. RANKED: slot = off[o] + pos_local[e] (two
// loads, NO atomics). Per-lane bf16 short stores.
// A layout (verified r4/r5): lane(lg,lr) row=rt*16+lr, k=ks*32+lg*8..+8.
// C/D: channel = ct*16+lr, row = rt*16 + lg*4 + j.
// ---------------------------------------------------------------------------
template<bool BF16G, bool RANKED>
__global__ __launch_bounds__(256, 4) void mfma_contrib(
    const float* __restrict__ x, const unsigned short* __restrict__ xb,
    const unsigned short* __restrict__ wt,
    const int* __restrict__ in_idx, const int* __restrict__ out_idx,
    const unsigned* __restrict__ offf, unsigned* __restrict__ cursor,
    const unsigned* __restrict__ pos_local, unsigned short* __restrict__ contrib)
{
    const int gwave = blockIdx.x * 4 + (threadIdx.x >> 6);
    if (gwave >= TOTAL_WT) return;
    const int lane = threadIdx.x & 63;
    const int lg = lane >> 4;            // 0..3
    const int lr = lane & 15;            // 0..15

    const int k  = gwave / TILES_PER_K;
    const int t  = gwave % TILES_PER_K;
    const int m0 = t * 64;
    const int kbase = k * M_PAIRS;

    // B fragments: bfr[ks][ct] holds wt[k][ct*16+lr][ks*32+lg*8 .. +8]
    short8 bfr[2][4];
    const unsigned short* wtk = wt + (size_t)k * C_DIM * C_DIM;
#pragma unroll
    for (int ks = 0; ks < 2; ++ks)
#pragma unroll
        for (int ct = 0; ct < 4; ++ct)
            bfr[ks][ct] = *(const short8*)(wtk + (ct * 16 + lr) * C_DIM + ks * 32 + lg * 8);

    // Slot for this lane's row (lane = row within tile).
    int pos = -1;
    {
        const int mrow = m0 + lane;
        if (mrow < M_PAIRS) {
            const int e = kbase + mrow;
            if constexpr (RANKED)
                pos = (int)(offf[out_idx[e]] + pos_local[e]);
            else
                pos = (int)atomicAdd(&cursor[out_idx[e]], 1u);
        }
    }

    // Row gather indices for A (this lane serves row rt*16+lr)
    int aidx[4];
#pragma unroll
    for (int rt = 0; rt < 4; ++rt) {
        const int m = m0 + rt * 16 + lr;
        aidx[rt] = (m < M_PAIRS) ? in_idx[kbase + m] : -1;
    }

    f32x4 acc[4][4] = {};
#pragma unroll
    for (int ks = 0; ks < 2; ++ks) {
#pragma unroll
        for (int rt = 0; rt < 4; ++rt) {
            short8 a = {};
            if (aidx[rt] >= 0) {
                if constexpr (BF16G) {
                    a = *(const short8*)(xb + (size_t)aidx[rt] * C_DIM + ks * 32 + lg * 8);
                } else {
                    const float* xr = x + (size_t)aidx[rt] * C_DIM + ks * 32 + lg * 8;
                    float4 f0 = *(const float4*)xr;
                    float4 f1 = *(const float4*)(xr + 4);
                    a[0] = (short)f32_to_bf16(f0.x); a[1] = (short)f32_to_bf16(f0.y);
                    a[2] = (short)f32_to_bf16(f0.z); a[3] = (short)f32_to_bf16(f0.w);
                    a[4] = (short)f32_to_bf16(f1.x); a[5] = (short)f32_to_bf16(f1.y);
                    a[6] = (short)f32_to_bf16(f1.z); a[7] = (short)f32_to_bf16(f1.w);
                }
            }
#pragma unroll
            for (int ct = 0; ct < 4; ++ct)
                acc[rt][ct] = __builtin_amdgcn_mfma_f32_16x16x32_bf16(
                    a, bfr[ks][ct], acc[rt][ct], 0, 0, 0);
        }
    }

    // Store contrib rows: row r = rt*16 + lg*4 + j; channel d = ct*16 + lr.
#pragma unroll
    for (int rt = 0; rt < 4; ++rt) {
#pragma unroll
        for (int j = 0; j < 4; ++j) {
            const int r = rt * 16 + lg * 4 + j;
            const int p = __shfl(pos, r);
            if (p >= 0) {
                unsigned short* dst = contrib + (size_t)p * C_DIM + lr;
#pragma unroll
                for (int ct = 0; ct < 4; ++ct)
                    dst[ct * 16] = f32_to_bf16(acc[rt][ct][j]);
            }
        }
    }
}

// ---------------------------------------------------------------------------
// Phase 2: streaming segmented reduce + fused BN stats. r14's proven
// structure (ushort4 loads, lg/lr layout, synchronized strided window,
// 2048 blocks) + DUAL-O INTERLEAVE: each wave processes o and o+NW
// concurrently -> 2 independent loads per inner iteration (2x MLP) at
// +~10 VGPR, no launch_bounds cap (r15's cap caused spill: WRITE 32->111MB),
// no lane-layout change (r13's unroll collapsed occupancy).
// ---------------------------------------------------------------------------
__global__ __launch_bounds__(256) void reduce_bn(
    const unsigned short* __restrict__ contrib, const unsigned* __restrict__ off,
    const unsigned* __restrict__ cnt, float* __restrict__ out,
    float* __restrict__ stats)
{
    __shared__ float ls[128];
    if (threadIdx.x < 128) ls[threadIdx.x] = 0.f;
    __syncthreads();
    const int lane = threadIdx.x & 63;
    const int lg = lane >> 4;            // row sub-slot 0..3
    const int lr = lane & 15;            // channel quad index 0..15
    const int wid  = blockIdx.x * 4 + (threadIdx.x >> 6);
    const int NW   = gridDim.x * 4;      // 8192 waves = full residency

    float ts0 = 0, ts1 = 0, ts2 = 0, ts3 = 0;
    float tq0 = 0, tq1 = 0, tq2 = 0, tq3 = 0;
    for (int o = wid; o < N_OUT_C; o += 2 * NW) {
        const int oA = o;
        const int oB = o + NW;
        const bool hasB = (oB < N_OUT_C);
        const unsigned baseA = off[oA];
        const int nA = (int)cnt[oA];
        const unsigned baseB = hasB ? off[oB] : 0u;
        const int nB = hasB ? (int)cnt[oB] : 0;
        const unsigned short* pA = contrib + (size_t)baseA * C_DIM + lr * 4;
        const unsigned short* pB = contrib + (size_t)baseB * C_DIM + lr * 4;

        float a0 = 0, a1 = 0, a2 = 0, a3 = 0;
        float b0 = 0, b1 = 0, b2 = 0, b3 = 0;
        const int nmax = (nA > nB) ? nA : nB;
        for (int i = lg; i < nmax; i += 4) {
            ushort4 uA = {0, 0, 0, 0}, uB = {0, 0, 0, 0};
            if (i < nA) uA = *(const ushort4*)(pA + (size_t)i * C_DIM);
            if (i < nB) uB = *(const ushort4*)(pB + (size_t)i * C_DIM);
            a0 += bf16f(uA.x); a1 += bf16f(uA.y);
            a2 += bf16f(uA.z); a3 += bf16f(uA.w);
            b0 += bf16f(uB.x); b1 += bf16f(uB.y);
            b2 += bf16f(uB.z); b3 += bf16f(uB.w);
        }

        a0 += __shfl_xor(a0, 16); a1 += __shfl_xor(a1, 16);
        a2 += __shfl_xor(a2, 16); a3 += __shfl_xor(a3, 16);
        a0 += __shfl_xor(a0, 32); a1 += __shfl_xor(a1, 32);
        a2 += __shfl_xor(a2, 32); a3 += __shfl_xor(a3, 32);
        b0 += __shfl_xor(b0, 16); b1 += __shfl_xor(b1, 16);
        b2 += __shfl_xor(b2, 16); b3 += __shfl_xor(b3, 16);
        b0 += __shfl_xor(b0, 32); b1 += __shfl_xor(b1, 32);
        b2 += __shfl_xor(b2, 32); b3 += __shfl_xor(b3, 32);

        if (lg == 0) {
            *(float4*)(out + (size_t)oA * C_DIM + lr * 4) =
                make_float4(a0, a1, a2, a3);
            ts0 += a0; tq0 = fmaf(a0, a0, tq0);
            ts1 += a1; tq1 = fmaf(a1, a1, tq1);
            ts2 += a2; tq2 = fmaf(a2, a2, tq2);
            ts3 += a3; tq3 = fmaf(a3, a3, tq3);
            if (hasB) {
                *(float4*)(out + (size_t)oB * C_DIM + lr * 4) =
                    make_float4(b0, b1, b2, b3);
                ts0 += b0; tq0 = fmaf(b0, b0, tq0);
                ts1 += b1; tq1 = fmaf(b1, b1, tq1);
                ts2 += b2; tq2 = fmaf(b2, b2, tq2);
                ts3 += b3; tq3 = fmaf(b3, b3, tq3);
            }
        }
    }
    if (lg == 0) {
        atomicAdd(&ls[lr * 4 + 0], ts0); atomicAdd(&ls[lr * 4 + 1], ts1);
        atomicAdd(&ls[lr * 4 + 2], ts2); atomicAdd(&ls[lr * 4 + 3], ts3);
        atomicAdd(&ls[64 + lr * 4 + 0], tq0); atomicAdd(&ls[64 + lr * 4 + 1], tq1);
        atomicAdd(&ls[64 + lr * 4 + 2], tq2); atomicAdd(&ls[64 + lr * 4 + 3], tq3);
    }
    __syncthreads();
    if (threadIdx.x < 128) unsafeAtomicAdd(&stats[threadIdx.x], ls[threadIdx.x]);
}

// ---- BN apply (in-place on f32 out; final write nontemporal) --------------
__global__ __launch_bounds__(256) void bn_apply_f32(
    float* __restrict__ out, const float* __restrict__ stats,
    const float* __restrict__ gamma, const float* __restrict__ beta)
{
    __shared__ float ssc[C_DIM], ssh[C_DIM];
    if (threadIdx.x < C_DIM) {
        const float inv_n = 1.0f / (float)N_OUT_C;
        float mean = stats[threadIdx.x] * inv_n;
        float var  = stats[C_DIM + threadIdx.x] * inv_n - mean * mean;
        float inv  = rsqrtf(var + BN_EPS);
        float s    = inv * gamma[threadIdx.x];
        ssc[threadIdx.x] = s;
        ssh[threadIdx.x] = beta[threadIdx.x] - mean * s;
    }
    __syncthreads();
    const int tid = blockIdx.x * blockDim.x + threadIdx.x;
    const int T   = gridDim.x * blockDim.x;
    const int cq  = (tid & 15) * 4;
    const int total4 = N_OUT_C * C_DIM / 4;
    const f32x4 sc = {ssc[cq], ssc[cq+1], ssc[cq+2], ssc[cq+3]};
    const f32x4 sh = {ssh[cq], ssh[cq+1], ssh[cq+2], ssh[cq+3]};
    f32x4* o4 = (f32x4*)out;
    for (int i = tid; i < total4; i += T) {
        f32x4 v = o4[i];
        v = v * sc + sh;
        __builtin_nontemporal_store(v, &o4[i]);
    }
}

// ===========================================================================
// Fallback (tiny ws): round-3 scalar path, f32 atomics into d_out.
// ===========================================================================
#define FCHUNKS  37
#define FWPK     (FCHUNKS * 4)
#define FSPAN    ((M_PAIRS + FWPK - 1) / FWPK)

__global__ __launch_bounds__(256, 4) void conv_scatter(
    const float* __restrict__ x, const float* __restrict__ W,
    const int* __restrict__ in_idx, const int* __restrict__ out_idx,
    float* __restrict__ out)
{
    const int k     = blockIdx.x / FCHUNKS;
    const int chunk = blockIdx.x % FCHUNKS;
    const int wid   = chunk * 4 + (threadIdx.x >> 6);
    const int lane  = threadIdx.x & 63;
    float wcol[C_DIM];
    const float* Wk = W + (size_t)k * C_DIM * C_DIM;
#pragma unroll
    for (int c = 0; c < C_DIM; ++c) wcol[c] = Wk[c * C_DIM + lane];
    const int kbase = k * M_PAIRS;
    const int m0 = wid * FSPAN;
    const int m1 = (m0 + FSPAN < M_PAIRS) ? m0 + FSPAN : M_PAIRS;
    for (int m = m0; m < m1; ++m) {
        int ii = __builtin_amdgcn_readfirstlane(in_idx[kbase + m]);
        int oi = __builtin_amdgcn_readfirstlane(out_idx[kbase + m]);
        const float* xr = x + (size_t)ii * C_DIM;
        float a0=0.f,a1=0.f,a2=0.f,a3=0.f;
#pragma unroll
        for (int c = 0; c < C_DIM; c += 4) {
            a0 = fmaf(xr[c+0], wcol[c+0], a0);
            a1 = fmaf(xr[c+1], wcol[c+1], a1);
            a2 = fmaf(xr[c+2], wcol[c+2], a2);
            a3 = fmaf(xr[c+3], wcol[c+3], a3);
        }
        unsafeAtomicAdd(out + (size_t)oi * C_DIM + lane, (a0+a1)+(a2+a3));
    }
}

__global__ __launch_bounds__(256) void bn_stats_f32(
    const float* __restrict__ acc, float* __restrict__ stats)
{
    const int tid = blockIdx.x * blockDim.x + threadIdx.x;
    const int T   = gridDim.x * blockDim.x;
    const int cq  = (tid & 15) * 4;
    const int total4 = N_OUT_C * C_DIM / 4;
    float s0=0,s1=0,s2=0,s3=0,q0=0,q1=0,q2=0,q3=0;
    const float4* a4 = (const float4*)acc;
    for (int i = tid; i < total4; i += T) {
        float4 v = a4[i];
        s0+=v.x; q0=fmaf(v.x,v.x,q0);
        s1+=v.y; q1=fmaf(v.y,v.y,q1);
        s2+=v.z; q2=fmaf(v.z,v.z,q2);
        s3+=v.w; q3=fmaf(v.w,v.w,q3);
    }
    __shared__ float ls[128];
    if (threadIdx.x < 128) ls[threadIdx.x] = 0.f;
    __syncthreads();
    atomicAdd(&ls[cq+0],s0); atomicAdd(&ls[cq+1],s1);
    atomicAdd(&ls[cq+2],s2); atomicAdd(&ls[cq+3],s3);
    atomicAdd(&ls[64+cq+0],q0); atomicAdd(&ls[64+cq+1],q1);
    atomicAdd(&ls[64+cq+2],q2); atomicAdd(&ls[64+cq+3],q3);
    __syncthreads();
    if (threadIdx.x < 128) unsafeAtomicAdd(&stats[threadIdx.x], ls[threadIdx.x]);
}

__global__ __launch_bounds__(256) void bn_apply_fb(
    float* __restrict__ out, const float* __restrict__ stats,
    const float* __restrict__ gamma, const float* __restrict__ beta)
{
    __shared__ float ssc[C_DIM], ssh[C_DIM];
    if (threadIdx.x < C_DIM) {
        const float inv_n = 1.0f / (float)N_OUT_C;
        float mean = stats[threadIdx.x] * inv_n;
        float var  = stats[C_DIM + threadIdx.x] * inv_n - mean * mean;
        float inv  = rsqrtf(var + BN_EPS);
        float s    = inv * gamma[threadIdx.x];
        ssc[threadIdx.x] = s;
        ssh[threadIdx.x] = beta[threadIdx.x] - mean * s;
    }
    __syncthreads();
    const int tid = blockIdx.x * blockDim.x + threadIdx.x;
    const int T   = gridDim.x * blockDim.x;
    const int cq  = (tid & 15) * 4;
    const int total4 = N_OUT_C * C_DIM / 4;
    const float4 sc = make_float4(ssc[cq], ssc[cq+1], ssc[cq+2], ssc[cq+3]);
    const float4 sh = make_float4(ssh[cq], ssh[cq+1], ssh[cq+2], ssh[cq+3]);
    float4* o4 = (float4*)out;
    for (int i = tid; i < total4; i += T) {
        float4 v = o4[i];
        v.x = fmaf(v.x, sc.x, sh.x);
        v.y = fmaf(v.y, sc.y, sh.y);
        v.z = fmaf(v.z, sc.z, sh.z);
        v.w = fmaf(v.w, sc.w, sh.w);
        o4[i] = v;
    }
}

// ---------------------------------------------------------------------------
extern "C" void kernel_launch(void* const* d_in, const int* in_sizes, int n_in,
                              void* d_out, int out_size, void* d_ws, size_t ws_size,
                              hipStream_t stream)
{
    const float* x       = (const float*)d_in[0];
    const float* W       = (const float*)d_in[1];
    const float* gamma   = (const float*)d_in[2];
    const float* beta    = (const float*)d_in[3];
    const int*   in_idx  = (const int*)d_in[4];
    const int*   out_idx = (const int*)d_in[5];
    float* out = (float*)d_out;

    if (ws_size >= WS_MID) {
        unsigned short* contrib = (unsigned short*)d_ws;
        unsigned short* wt      = (unsigned short*)((char*)d_ws + WT_OFF);
        unsigned* cnt           = (unsigned*)((char*)d_ws + CNT_OFF);
        unsigned* off           = (unsigned*)((char*)d_ws + OFF_OFF);
        unsigned* cur           = (unsigned*)((char*)d_ws + CUR_OFF);
        unsigned* bsum          = (unsigned*)((char*)d_ws + BSUM_OFF);
        float* stats            = (float*)((char*)d_ws + ST_OFF);
        unsigned short* xb      = (unsigned short*)((char*)d_ws + XB_OFF);

        const bool full   = (ws_size >= WS_FULL);
        const bool ranked = full ? (ws_size >= WS_T1) : (ws_size >= WS_T3);
        unsigned* pos = ranked
            ? (unsigned*)((char*)d_ws + (full ? (XB_OFF + XB_BYTES) : XB_OFF))
            : nullptr;
        const int nx = full ? PREP_XBLK : 0;

        hipMemsetAsync(cnt, 0, CNT_BYTES, stream);
        hipMemsetAsync(stats, 0, 128 * sizeof(float), stream);
        prep<<<nx + PREP_WBLK + PREP_HBLK, 256, 0, stream>>>(
            x, xb, W, wt, out_idx, cnt, pos, nx);
        scan_a<<<SCAN_NB, SCAN_BS, 0, stream>>>(cnt, off, bsum);
        scan_b<<<1, 512, 0, stream>>>(bsum);
        scan_c<<<SCAN_NB, SCAN_BS, 0, stream>>>(off, cur, bsum);

        const int cgrid = (TOTAL_WT + 3) / 4;
        if (full && ranked)
            mfma_contrib<true, true><<<cgrid, 256, 0, stream>>>(
                x, xb, wt, in_idx, out_idx, off, cur, pos, contrib);
        else if (full)
            mfma_contrib<true, false><<<cgrid, 256, 0, stream>>>(
                x, xb, wt, in_idx, out_idx, off, cur, pos, contrib);
        else if (ranked)
            mfma_contrib<false, true><<<cgrid, 256, 0, stream>>>(
                x, xb, wt, in_idx, out_idx, off, cur, pos, contrib);
        else
            mfma_contrib<false, false><<<cgrid, 256, 0, stream>>>(
                x, xb, wt, in_idx, out_idx, off, cur, pos, contrib);

        reduce_bn<<<2048, 256, 0, stream>>>(contrib, off, cnt, out, stats);
        bn_apply_f32<<<1024, 256, 0, stream>>>(out, stats, gamma, beta);
    } else {
        float* stats = (float*)d_ws;
        hipMemsetAsync(out, 0, (size_t)N_OUT_C * C_DIM * sizeof(float), stream);
        hipMemsetAsync(stats, 0, 128 * sizeof(float), stream);
        conv_scatter<<<K_OFF * FCHUNKS, 256, 0, stream>>>(x, W, in_idx, out_idx, out);
        bn_stats_f32<<<512, 256, 0, stream>>>(out, stats);
        bn_apply_fb<<<1024, 256, 0, stream>>>(out, stats, gamma, beta);
    }
}